// Round 18
// baseline (166.521 us; speedup 1.0000x reference)
//
#include <hip/hip_runtime.h>
#include <hip/hip_bf16.h>
#include <cstdint>

#define NN 50000
#define NE 1200000
#define DD 128
#define RR 6
#define NEG 0.2f
#define NB 391          // ceil(NN/128) buckets of 128 nodes
#define CAP 4096        // slab capacity per bucket (mean 3072, std 55)
#define TILE 4096       // edges per bscatter block
#define GEMMB 782       // gemm blocks = ceil(NN/64)
#define SCB ((NE + TILE - 1) / TILE)   // 293 bscatter blocks
#define TOTB (GEMMB + SCB)             // 1075

typedef __hip_bfloat16 bf16;
typedef __attribute__((ext_vector_type(8))) short short8;
typedef __attribute__((ext_vector_type(4))) float f32x4;

__device__ __forceinline__ float bflo(unsigned u) { return __uint_as_float(u << 16); }
__device__ __forceinline__ float bfhi(unsigned u) { return __uint_as_float(u & 0xFFFF0000u); }
__device__ __forceinline__ ushort f2b(float v) {  // f32 -> bf16 RTNE
  unsigned b = __float_as_uint(v);
  return (ushort)((b + 0x7FFFu + ((b >> 16) & 1u)) >> 16);
}

// ------- prep: bcur zero + W B-frags (wp) + wq/wk frag (wp7) ---------------
__global__ __launch_bounds__(256) void k_prep(const float* __restrict__ W,
    const float* __restrict__ qv, const float* __restrict__ kv,
    ushort* __restrict__ wp, ushort* __restrict__ wp7, int* __restrict__ bcur) {
  int t = blockIdx.x * 256 + threadIdx.x;
  if (t < NB) bcur[t] = 0;
  if (t < RR * 8 * 4 * 64) {
    int lane = t & 63;
    int ks = (t >> 6) & 3;
    int cf = (t >> 8) & 7;
    int r = t >> 11;
    int col = cf * 16 + (lane & 15);
    int k0 = ks * 32 + (lane >> 4) * 8;
    ushort* dst = wp + (size_t)t * 8;
    #pragma unroll
    for (int e = 0; e < 8; ++e)
      dst[e] = f2b(W[((size_t)r * DD + (k0 + e)) * DD + col]);
  } else if (t < RR * 8 * 4 * 64 + 256) {
    int idx = t - RR * 8 * 4 * 64;
    int lane = idx & 63, ks = idx >> 6;
    int col = lane & 15;
    int k0 = ks * 32 + (lane >> 4) * 8;
    ushort* dst = wp7 + (size_t)idx * 8;
    #pragma unroll
    for (int e = 0; e < 8; ++e) {
      float v = 0.f;
      if (col < 12) {
        int r = col < 6 ? col : col - 6;
        const float* vv = col < 6 ? qv : kv;
        const float* row = W + ((size_t)r * DD + (k0 + e)) * DD;
        for (int o = 0; o < DD; ++o) v += row[o] * vv[o];
      }
      dst[e] = f2b(v);
    }
  }
}

// ---- fused gemm+bscatter, Bresenham-interleaved block types ---------------
// bscatter now stages nothing: pass1 reads dst, pass2 re-reads ei/et (L2-hot)
union FSMem {
  ushort tile[64][136];                  // gemm LDS staging (17.4 KB)
  struct { int lh[NB], lbase[NB], lcur[NB]; } c;   // bscatter (4.7 KB)
};

__global__ __launch_bounds__(256) void k_fused(const float* __restrict__ x,
    const ushort* __restrict__ wp, const ushort* __restrict__ wp7,
    const int* __restrict__ ei, const int* __restrict__ et,
    int* __restrict__ bcur, unsigned* __restrict__ bedge,
    ushort* __restrict__ hx, float* __restrict__ nq, float* __restrict__ nk) {
  __shared__ FSMem sm;
  int tid = threadIdx.x;
  int bid = blockIdx.x;
  int scb0 = (int)(((long long)bid * SCB) / TOTB);
  int scb1 = (int)(((long long)(bid + 1) * SCB) / TOTB);

  if (scb1 > scb0) {
    // ---------------- bscatter block (sc_id = scb0) ----------------
    int e0 = scb0 * TILE;
    int lim = NE - e0; if (lim > TILE) lim = TILE;
    for (int i = tid; i < NB; i += 256) sm.c.lh[i] = 0;
    __syncthreads();
    for (int i = tid; i < lim; i += 256)
      atomicAdd(&sm.c.lh[ei[NE + e0 + i] >> 7], 1);
    __syncthreads();
    for (int i = tid; i < NB; i += 256) {
      int c = sm.c.lh[i];
      sm.c.lbase[i] = c ? atomicAdd(&bcur[i], c) : 0;
      sm.c.lcur[i] = 0;
    }
    __syncthreads();
    for (int i = tid; i < lim; i += 256) {
      int e = e0 + i;
      int s = ei[e], d = ei[NE + e], r = et[e];
      unsigned rowid = (unsigned)(r * NN + s);
      unsigned val = (rowid << 3) | (unsigned)r | ((unsigned)(d & 127) << 22);
      int b = d >> 7;
      int pos = b * CAP + sm.c.lbase[b] + atomicAdd(&sm.c.lcur[b], 1);
      bedge[pos] = val;
    }
    return;
  }

  // ---------------- gemm block (gemm_id = bid - scb0) ----------------
  int gb = bid - scb0;
  int w = tid >> 6, l = tid & 63;
  int wrow = w & 1, wcol = w >> 1;
  int row0 = gb * 64;
  int rbase = row0 + wrow * 32;
  int lr = l & 15, lg = l >> 4;

  short8 af[2][4];
  #pragma unroll
  for (int rf = 0; rf < 2; ++rf) {
    int row = rbase + rf * 16 + lr;
    row = row < NN ? row : NN - 1;
    const float* src = x + (size_t)row * DD + lg * 8;
    #pragma unroll
    for (int ks = 0; ks < 4; ++ks) {
      float4 u0 = *reinterpret_cast<const float4*>(src + ks * 32);
      float4 u1 = *reinterpret_cast<const float4*>(src + ks * 32 + 4);
      short8 a;
      a[0] = (short)f2b(u0.x); a[1] = (short)f2b(u0.y);
      a[2] = (short)f2b(u0.z); a[3] = (short)f2b(u0.w);
      a[4] = (short)f2b(u1.x); a[5] = (short)f2b(u1.y);
      a[6] = (short)f2b(u1.z); a[7] = (short)f2b(u1.w);
      af[rf][ks] = a;
    }
  }

  if (wcol == 0) {
    f32x4 aq0 = {0.f, 0.f, 0.f, 0.f}, aq1 = {0.f, 0.f, 0.f, 0.f};
    #pragma unroll
    for (int ks = 0; ks < 4; ++ks) {
      short8 b = *reinterpret_cast<const short8*>(wp7 + (size_t)(ks * 64 + l) * 8);
      aq0 = __builtin_amdgcn_mfma_f32_16x16x32_bf16(af[0][ks], b, aq0, 0, 0, 0);
      aq1 = __builtin_amdgcn_mfma_f32_16x16x32_bf16(af[1][ks], b, aq1, 0, 0, 0);
    }
    if (lr < 12) {
      float* pl = (lr < 6 ? nq + (size_t)lr * NN : nk + (size_t)(lr - 6) * NN);
      #pragma unroll
      for (int rf = 0; rf < 2; ++rf) {
        int rowb = rbase + rf * 16 + lg * 4;
        f32x4 v = rf ? aq1 : aq0;
        if (rowb + 3 < NN) {
          float4 o4 = make_float4(v[0], v[1], v[2], v[3]);
          *reinterpret_cast<float4*>(pl + rowb) = o4;
        } else {
          #pragma unroll
          for (int j = 0; j < 4; ++j) if (rowb + j < NN) pl[rowb + j] = v[j];
        }
      }
    }
  }

  for (int r = 0; r < RR; ++r) {
    #pragma unroll
    for (int cfl = 0; cfl < 4; ++cfl) {
      int cfg = wcol * 4 + cfl;
      const ushort* bp = wp + (((size_t)(r * 8 + cfg) * 4) * 64 + l) * 8;
      short8 b0 = *reinterpret_cast<const short8*>(bp);
      short8 b1 = *reinterpret_cast<const short8*>(bp + 512);
      short8 b2 = *reinterpret_cast<const short8*>(bp + 1024);
      short8 b3 = *reinterpret_cast<const short8*>(bp + 1536);
      f32x4 acc0 = {0.f, 0.f, 0.f, 0.f};
      f32x4 acc1 = {0.f, 0.f, 0.f, 0.f};
      acc0 = __builtin_amdgcn_mfma_f32_16x16x32_bf16(af[0][0], b0, acc0, 0, 0, 0);
      acc1 = __builtin_amdgcn_mfma_f32_16x16x32_bf16(af[1][0], b0, acc1, 0, 0, 0);
      acc0 = __builtin_amdgcn_mfma_f32_16x16x32_bf16(af[0][1], b1, acc0, 0, 0, 0);
      acc1 = __builtin_amdgcn_mfma_f32_16x16x32_bf16(af[1][1], b1, acc1, 0, 0, 0);
      acc0 = __builtin_amdgcn_mfma_f32_16x16x32_bf16(af[0][2], b2, acc0, 0, 0, 0);
      acc1 = __builtin_amdgcn_mfma_f32_16x16x32_bf16(af[1][2], b2, acc1, 0, 0, 0);
      acc0 = __builtin_amdgcn_mfma_f32_16x16x32_bf16(af[0][3], b3, acc0, 0, 0, 0);
      acc1 = __builtin_amdgcn_mfma_f32_16x16x32_bf16(af[1][3], b3, acc1, 0, 0, 0);

      int col = cfg * 16 + lr;
      #pragma unroll
      for (int rf = 0; rf < 2; ++rf) {
        int rowrel = wrow * 32 + rf * 16 + lg * 4;
        f32x4 ac = rf ? acc1 : acc0;
        #pragma unroll
        for (int j = 0; j < 4; ++j)
          sm.tile[rowrel + j][col] = f2b(ac[j]);
      }
    }
    __syncthreads();
    #pragma unroll
    for (int it = 0; it < 4; ++it) {
      int rowrel = (tid >> 4) + it * 16;
      int grow = row0 + rowrel;
      uint4 v = *reinterpret_cast<const uint4*>(&sm.tile[rowrel][(tid & 15) * 8]);
      if (grow < NN)
        *reinterpret_cast<uint4*>(hx + ((size_t)r * NN + grow) * DD + (tid & 15) * 8) = v;
    }
    __syncthreads();
  }
}

// ------- per-bucket (128 nodes): deg, offs, rec = rowid<<13 | p13 ----------
// p13: 13-bit float (8exp+5mant, RTNE) of exp(leaky(logit)); rel err <=2^-6
__global__ __launch_bounds__(256) void k_bfinal(const unsigned* __restrict__ bedge,
    const int* __restrict__ bcur,
    const float* __restrict__ nq, const float* __restrict__ nk,
    int* __restrict__ deg, int* __restrict__ offs, unsigned* __restrict__ rec) {
  __shared__ int lh[128], sc_s[128], lcur[128];
  int b = blockIdx.x, tid = threadIdx.x;
  int base = b * CAP, cnt = bcur[b];
  if (tid < 128) lh[tid] = 0;
  __syncthreads();
  for (int i = tid; i < cnt; i += 256)
    atomicAdd(&lh[(bedge[base + i] >> 22) & 127], 1);
  __syncthreads();
  int v = 0;
  if (tid < 128) { v = lh[tid]; sc_s[tid] = v; }
  __syncthreads();
  for (int off = 1; off < 128; off <<= 1) {
    int u = (tid < 128 && tid >= off) ? sc_s[tid - off] : 0;
    __syncthreads();
    if (tid < 128) sc_s[tid] += u;
    __syncthreads();
  }
  if (tid < 128) {
    int excl = sc_s[tid] - v;
    int n = (b << 7) + tid;
    if (n < NN) { deg[n] = v; offs[n] = base + excl; }
    lcur[tid] = base + excl;
  }
  __syncthreads();
  for (int i = tid; i < cnt; i += 256) {
    unsigned be = bedge[base + i];
    unsigned rowid = (be >> 3) & 0x7FFFFu;
    int r = (int)(be & 7u);
    int dloc = (int)((be >> 22) & 127u);
    float l = nq[(size_t)r * NN + (b << 7) + dloc] + nk[rowid];
    l = l > 0.f ? l : NEG * l;
    float p = __expf(l);     // logits O(1): exp without max-sub is exact-safe
    unsigned pb = (__float_as_uint(p) + 0x20000u) >> 18;   // RTNE to 8e+5m
    int pos = atomicAdd(&lcur[dloc], 1);
    rec[pos] = (rowid << 13) | (pb & 0x1FFFu);
  }
}

// ------- gather-aggregate: p-weighted accumulate (8-deep, 32-lane) ---------
__global__ __launch_bounds__(256) void k_agg(const float* __restrict__ x,
    const float* __restrict__ bias, const int* __restrict__ offs,
    const int* __restrict__ deg, const unsigned* __restrict__ rec,
    const bf16* __restrict__ hx, float* __restrict__ out,
    float* __restrict__ irec) {
  int g = threadIdx.x >> 5, lane = threadIdx.x & 31;
  int n = blockIdx.x * 8 + g;
  if (n >= NN) return;
  int base = offs[n], cnt = deg[n];
  const char* hp = (const char*)hx;
  int lo8 = lane * 8;

  float ssum = 0.f;
  float a0 = 0.f, a1 = 0.f, a2 = 0.f, a3 = 0.f;

#define DEC(E, OFF, P) unsigned OFF = ((E) >> 5) & 0xFFFFFF00u; \
                       float P = __uint_as_float(((E) & 0x1FFFu) << 18);

  int j = 0;
  for (; j + 7 < cnt; j += 8) {
    unsigned e0 = rec[base + j],     e1 = rec[base + j + 1];
    unsigned e2 = rec[base + j + 2], e3 = rec[base + j + 3];
    unsigned e4 = rec[base + j + 4], e5 = rec[base + j + 5];
    unsigned e6 = rec[base + j + 6], e7 = rec[base + j + 7];
    DEC(e0, o0, p0) DEC(e1, o1, p1) DEC(e2, o2, p2) DEC(e3, o3, p3)
    DEC(e4, o4, p4) DEC(e5, o5, p5) DEC(e6, o6, p6) DEC(e7, o7, p7)
    uint2 q0 = *reinterpret_cast<const uint2*>(hp + o0 + lo8);
    uint2 q1 = *reinterpret_cast<const uint2*>(hp + o1 + lo8);
    uint2 q2 = *reinterpret_cast<const uint2*>(hp + o2 + lo8);
    uint2 q3 = *reinterpret_cast<const uint2*>(hp + o3 + lo8);
    uint2 q4 = *reinterpret_cast<const uint2*>(hp + o4 + lo8);
    uint2 q5 = *reinterpret_cast<const uint2*>(hp + o5 + lo8);
    uint2 q6 = *reinterpret_cast<const uint2*>(hp + o6 + lo8);
    uint2 q7 = *reinterpret_cast<const uint2*>(hp + o7 + lo8);
    ssum += ((p0 + p1) + (p2 + p3)) + ((p4 + p5) + (p6 + p7));
    a0 += p0 * bflo(q0.x) + p1 * bflo(q1.x) + p2 * bflo(q2.x) + p3 * bflo(q3.x)
        + p4 * bflo(q4.x) + p5 * bflo(q5.x) + p6 * bflo(q6.x) + p7 * bflo(q7.x);
    a1 += p0 * bfhi(q0.x) + p1 * bfhi(q1.x) + p2 * bfhi(q2.x) + p3 * bfhi(q3.x)
        + p4 * bfhi(q4.x) + p5 * bfhi(q5.x) + p6 * bfhi(q6.x) + p7 * bfhi(q7.x);
    a2 += p0 * bflo(q0.y) + p1 * bflo(q1.y) + p2 * bflo(q2.y) + p3 * bflo(q3.y)
        + p4 * bflo(q4.y) + p5 * bflo(q5.y) + p6 * bflo(q6.y) + p7 * bflo(q7.y);
    a3 += p0 * bfhi(q0.y) + p1 * bfhi(q1.y) + p2 * bfhi(q2.y) + p3 * bfhi(q3.y)
        + p4 * bfhi(q4.y) + p5 * bfhi(q5.y) + p6 * bfhi(q6.y) + p7 * bfhi(q7.y);
  }
  for (; j + 3 < cnt; j += 4) {
    unsigned e0 = rec[base + j],     e1 = rec[base + j + 1];
    unsigned e2 = rec[base + j + 2], e3 = rec[base + j + 3];
    DEC(e0, o0, p0) DEC(e1, o1, p1) DEC(e2, o2, p2) DEC(e3, o3, p3)
    uint2 q0 = *reinterpret_cast<const uint2*>(hp + o0 + lo8);
    uint2 q1 = *reinterpret_cast<const uint2*>(hp + o1 + lo8);
    uint2 q2 = *reinterpret_cast<const uint2*>(hp + o2 + lo8);
    uint2 q3 = *reinterpret_cast<const uint2*>(hp + o3 + lo8);
    ssum += (p0 + p1) + (p2 + p3);
    a0 += p0 * bflo(q0.x) + p1 * bflo(q1.x) + p2 * bflo(q2.x) + p3 * bflo(q3.x);
    a1 += p0 * bfhi(q0.x) + p1 * bfhi(q1.x) + p2 * bfhi(q2.x) + p3 * bfhi(q3.x);
    a2 += p0 * bflo(q0.y) + p1 * bflo(q1.y) + p2 * bflo(q2.y) + p3 * bflo(q3.y);
    a3 += p0 * bfhi(q0.y) + p1 * bfhi(q1.y) + p2 * bfhi(q2.y) + p3 * bfhi(q3.y);
  }
  for (; j < cnt; ++j) {
    unsigned e0 = rec[base + j];
    DEC(e0, o0, p0)
    uint2 q0 = *reinterpret_cast<const uint2*>(hp + o0 + lo8);
    ssum += p0;
    a0 += p0 * bflo(q0.x);
    a1 += p0 * bfhi(q0.x);
    a2 += p0 * bflo(q0.y);
    a3 += p0 * bfhi(q0.y);
  }
#undef DEC

  float inv = 1.f / (ssum + 1e-16f);
  size_t o = (size_t)n * DD + lane * 4;
  float4 xb = *reinterpret_cast<const float4*>(x + o);
  float4 bb = *reinterpret_cast<const float4*>(bias + lane * 4);
  float4 res;
  res.x = xb.x + bb.x + a0 * inv;
  res.y = xb.y + bb.y + a1 * inv;
  res.z = xb.z + bb.z + a2 * inv;
  res.w = xb.w + bb.w + a3 * inv;
  *reinterpret_cast<float4*>(out + o) = res;

  if (lane == 0) irec[n] = inv;
}

// ---------------- alpha in original edge order (2 edges/thread) ------------
__global__ __launch_bounds__(256) void k_alpha(const int* __restrict__ ei,
    const int* __restrict__ et, const float* __restrict__ nq,
    const float* __restrict__ nk, const float* __restrict__ irec,
    float* __restrict__ alpha) {
  int e = (blockIdx.x * 256 + threadIdx.x) * 2;
  if (e >= NE) return;   // NE even -> pair always complete
  int2 ss = *reinterpret_cast<const int2*>(ei + e);
  int2 dd = *reinterpret_cast<const int2*>(ei + NE + e);
  int2 rr = *reinterpret_cast<const int2*>(et + e);
  float l0 = nq[(size_t)rr.x * NN + dd.x] + nk[(size_t)rr.x * NN + ss.x];
  float l1 = nq[(size_t)rr.y * NN + dd.y] + nk[(size_t)rr.y * NN + ss.y];
  l0 = l0 > 0.f ? l0 : NEG * l0;
  l1 = l1 > 0.f ? l1 : NEG * l1;
  float2 res;
  res.x = __expf(l0) * irec[dd.x];
  res.y = __expf(l1) * irec[dd.y];
  *reinterpret_cast<float2*>(alpha + e) = res;
}

extern "C" void kernel_launch(void* const* d_in, const int* in_sizes, int n_in,
                              void* d_out, int out_size, void* d_ws, size_t ws_size,
                              hipStream_t stream) {
  const float* x    = (const float*)d_in[0];
  const int*   ei   = (const int*)d_in[1];
  const int*   et   = (const int*)d_in[2];
  const float* W    = (const float*)d_in[3];
  const float* qv   = (const float*)d_in[4];
  const float* kv   = (const float*)d_in[5];
  const float* bias = (const float*)d_in[6];

  float* out   = (float*)d_out;              // [NN*DD]
  float* alpha = out + (size_t)NN * DD;      // [NE]

  char* p = (char*)d_ws;
  bf16*  hx      = (bf16*)p;    p += (size_t)RR * NN * DD * sizeof(bf16); // 76.8 MB
  float* nq      = (float*)p;   p += (size_t)RR * NN * sizeof(float);
  float* nk      = (float*)p;   p += (size_t)RR * NN * sizeof(float);
  int*   deg     = (int*)p;     p += NN * sizeof(int);
  int*   offs    = (int*)p;     p += NN * sizeof(int);
  float* irec    = (float*)p;   p += NN * sizeof(float);
  int*   bcur    = (int*)p;     p += NB * sizeof(int);
  p = (char*)(((uintptr_t)p + 15) & ~(uintptr_t)15);
  unsigned* bedge = (unsigned*)p; p += (size_t)NB * CAP * sizeof(unsigned); // 6.4 MB
  unsigned* rec  = (unsigned*)p;  p += (size_t)NB * CAP * sizeof(unsigned); // 6.4 MB
  ushort* wp     = (ushort*)p;  p += (size_t)RR * 8 * 4 * 64 * 8 * sizeof(ushort); // 196 KB
  ushort* wp7    = (ushort*)p;  p += (size_t)4 * 64 * 8 * sizeof(ushort);          // 4 KB

  k_prep<<<49, 256, 0, stream>>>(W, qv, kv, wp, wp7, bcur);
  k_fused<<<TOTB, 256, 0, stream>>>(x, wp, wp7, ei, et, bcur, bedge,
                                    (ushort*)hx, nq, nk);
  k_bfinal<<<NB, 256, 0, stream>>>(bedge, bcur, nq, nk, deg, offs, rec);
  k_agg<<<(NN + 7) / 8, 256, 0, stream>>>(x, bias, offs, deg, rec, hx, out, irec);
  k_alpha<<<(NE / 2 + 255) / 256, 256, 0, stream>>>(ei, et, nq, nk, irec, alpha);
}

// Round 19
// 159.208 us; speedup vs baseline: 1.0459x; 1.0459x over previous
//
#include <hip/hip_runtime.h>
#include <hip/hip_bf16.h>
#include <cstdint>

#define NN 50000
#define NE 1200000
#define DD 128
#define RR 6
#define NEG 0.2f
#define NB 391          // ceil(NN/128) buckets of 128 nodes
#define CAP 4096        // slab capacity per bucket (mean 3072, std 55)
#define TILE 4096       // edges per bscatter block
#define GEMMB 782       // gemm blocks = ceil(NN/64)
#define SCB ((NE + TILE - 1) / TILE)   // 293 bscatter blocks

typedef __hip_bfloat16 bf16;
typedef __attribute__((ext_vector_type(8))) short short8;
typedef __attribute__((ext_vector_type(4))) float f32x4;

__device__ __forceinline__ float bflo(unsigned u) { return __uint_as_float(u << 16); }
__device__ __forceinline__ float bfhi(unsigned u) { return __uint_as_float(u & 0xFFFF0000u); }
__device__ __forceinline__ ushort f2b(float v) {  // f32 -> bf16 RTNE
  unsigned b = __float_as_uint(v);
  return (ushort)((b + 0x7FFFu + ((b >> 16) & 1u)) >> 16);
}

// ------- prep: bcur zero + W B-frags (wp) + wq/wk frag (wp7) ---------------
__global__ __launch_bounds__(256) void k_prep(const float* __restrict__ W,
    const float* __restrict__ qv, const float* __restrict__ kv,
    ushort* __restrict__ wp, ushort* __restrict__ wp7, int* __restrict__ bcur) {
  int t = blockIdx.x * 256 + threadIdx.x;
  if (t < NB) bcur[t] = 0;
  if (t < RR * 8 * 4 * 64) {
    int lane = t & 63;
    int ks = (t >> 6) & 3;
    int cf = (t >> 8) & 7;
    int r = t >> 11;
    int col = cf * 16 + (lane & 15);
    int k0 = ks * 32 + (lane >> 4) * 8;
    ushort* dst = wp + (size_t)t * 8;
    #pragma unroll
    for (int e = 0; e < 8; ++e)
      dst[e] = f2b(W[((size_t)r * DD + (k0 + e)) * DD + col]);
  } else if (t < RR * 8 * 4 * 64 + 256) {
    int idx = t - RR * 8 * 4 * 64;
    int lane = idx & 63, ks = idx >> 6;
    int col = lane & 15;
    int k0 = ks * 32 + (lane >> 4) * 8;
    ushort* dst = wp7 + (size_t)idx * 8;
    #pragma unroll
    for (int e = 0; e < 8; ++e) {
      float v = 0.f;
      if (col < 12) {
        int r = col < 6 ? col : col - 6;
        const float* vv = col < 6 ? qv : kv;
        const float* row = W + ((size_t)r * DD + (k0 + e)) * DD;
        for (int o = 0; o < DD; ++o) v += row[o] * vv[o];
      }
      dst[e] = f2b(v);
    }
  }
}

// ---- fused: blocks [0,GEMMB) = MFMA GEMM+nqk ; [GEMMB,+SCB) = bscatter ----
union FSMem {
  ushort tile[64][136];                  // gemm LDS staging (17.4 KB)
  struct {                               // bscatter staging (29.3 KB)
    unsigned sval[TILE];
    unsigned short sbkt[TILE];
    int lh[NB], lbase[NB], lcur[NB];
  } c;
};

__global__ __launch_bounds__(256) void k_fused(const float* __restrict__ x,
    const ushort* __restrict__ wp, const ushort* __restrict__ wp7,
    const int* __restrict__ ei, const int* __restrict__ et,
    int* __restrict__ bcur, unsigned* __restrict__ bedge,
    ushort* __restrict__ hx, float* __restrict__ nq, float* __restrict__ nk) {
  __shared__ FSMem sm;
  int tid = threadIdx.x;

  if (blockIdx.x >= GEMMB) {
    // ---------------- bscatter part ----------------
    int blk = blockIdx.x - GEMMB;
    int e0 = blk * TILE;
    int lim = NE - e0; if (lim > TILE) lim = TILE;
    for (int i = tid; i < NB; i += 256) sm.c.lh[i] = 0;
    __syncthreads();
    for (int i = tid; i < lim; i += 256) {
      int e = e0 + i;
      int s = ei[e], d = ei[NE + e], r = et[e];
      unsigned rowid = (unsigned)(r * NN + s);
      sm.c.sval[i] = (rowid << 3) | (unsigned)r | ((unsigned)(d & 127) << 22);
      sm.c.sbkt[i] = (unsigned short)(d >> 7);
      atomicAdd(&sm.c.lh[d >> 7], 1);
    }
    __syncthreads();
    for (int i = tid; i < NB; i += 256) {
      int c = sm.c.lh[i];
      sm.c.lbase[i] = c ? atomicAdd(&bcur[i], c) : 0;
      sm.c.lcur[i] = 0;
    }
    __syncthreads();
    for (int i = tid; i < lim; i += 256) {
      int b = sm.c.sbkt[i];
      int pos = b * CAP + sm.c.lbase[b] + atomicAdd(&sm.c.lcur[b], 1);
      bedge[pos] = sm.c.sval[i];
    }
    return;
  }

  // ---------------- gemm part ----------------
  int w = tid >> 6, l = tid & 63;
  int wrow = w & 1, wcol = w >> 1;
  int row0 = blockIdx.x * 64;
  int rbase = row0 + wrow * 32;
  int lr = l & 15, lg = l >> 4;

  short8 af[2][4];
  #pragma unroll
  for (int rf = 0; rf < 2; ++rf) {
    int row = rbase + rf * 16 + lr;
    row = row < NN ? row : NN - 1;
    const float* src = x + (size_t)row * DD + lg * 8;
    #pragma unroll
    for (int ks = 0; ks < 4; ++ks) {
      float4 u0 = *reinterpret_cast<const float4*>(src + ks * 32);
      float4 u1 = *reinterpret_cast<const float4*>(src + ks * 32 + 4);
      short8 a;
      a[0] = (short)f2b(u0.x); a[1] = (short)f2b(u0.y);
      a[2] = (short)f2b(u0.z); a[3] = (short)f2b(u0.w);
      a[4] = (short)f2b(u1.x); a[5] = (short)f2b(u1.y);
      a[6] = (short)f2b(u1.z); a[7] = (short)f2b(u1.w);
      af[rf][ks] = a;
    }
  }

  if (wcol == 0) {
    f32x4 aq0 = {0.f, 0.f, 0.f, 0.f}, aq1 = {0.f, 0.f, 0.f, 0.f};
    #pragma unroll
    for (int ks = 0; ks < 4; ++ks) {
      short8 b = *reinterpret_cast<const short8*>(wp7 + (size_t)(ks * 64 + l) * 8);
      aq0 = __builtin_amdgcn_mfma_f32_16x16x32_bf16(af[0][ks], b, aq0, 0, 0, 0);
      aq1 = __builtin_amdgcn_mfma_f32_16x16x32_bf16(af[1][ks], b, aq1, 0, 0, 0);
    }
    if (lr < 12) {
      float* pl = (lr < 6 ? nq + (size_t)lr * NN : nk + (size_t)(lr - 6) * NN);
      #pragma unroll
      for (int rf = 0; rf < 2; ++rf) {
        int rowb = rbase + rf * 16 + lg * 4;
        f32x4 v = rf ? aq1 : aq0;
        if (rowb + 3 < NN) {
          float4 o4 = make_float4(v[0], v[1], v[2], v[3]);
          *reinterpret_cast<float4*>(pl + rowb) = o4;
        } else {
          #pragma unroll
          for (int j = 0; j < 4; ++j) if (rowb + j < NN) pl[rowb + j] = v[j];
        }
      }
    }
  }

  for (int r = 0; r < RR; ++r) {
    #pragma unroll
    for (int cfl = 0; cfl < 4; ++cfl) {
      int cfg = wcol * 4 + cfl;
      const ushort* bp = wp + (((size_t)(r * 8 + cfg) * 4) * 64 + l) * 8;
      short8 b0 = *reinterpret_cast<const short8*>(bp);
      short8 b1 = *reinterpret_cast<const short8*>(bp + 512);
      short8 b2 = *reinterpret_cast<const short8*>(bp + 1024);
      short8 b3 = *reinterpret_cast<const short8*>(bp + 1536);
      f32x4 acc0 = {0.f, 0.f, 0.f, 0.f};
      f32x4 acc1 = {0.f, 0.f, 0.f, 0.f};
      acc0 = __builtin_amdgcn_mfma_f32_16x16x32_bf16(af[0][0], b0, acc0, 0, 0, 0);
      acc1 = __builtin_amdgcn_mfma_f32_16x16x32_bf16(af[1][0], b0, acc1, 0, 0, 0);
      acc0 = __builtin_amdgcn_mfma_f32_16x16x32_bf16(af[0][1], b1, acc0, 0, 0, 0);
      acc1 = __builtin_amdgcn_mfma_f32_16x16x32_bf16(af[1][1], b1, acc1, 0, 0, 0);
      acc0 = __builtin_amdgcn_mfma_f32_16x16x32_bf16(af[0][2], b2, acc0, 0, 0, 0);
      acc1 = __builtin_amdgcn_mfma_f32_16x16x32_bf16(af[1][2], b2, acc1, 0, 0, 0);
      acc0 = __builtin_amdgcn_mfma_f32_16x16x32_bf16(af[0][3], b3, acc0, 0, 0, 0);
      acc1 = __builtin_amdgcn_mfma_f32_16x16x32_bf16(af[1][3], b3, acc1, 0, 0, 0);

      int col = cfg * 16 + lr;
      #pragma unroll
      for (int rf = 0; rf < 2; ++rf) {
        int rowrel = wrow * 32 + rf * 16 + lg * 4;
        f32x4 ac = rf ? acc1 : acc0;
        #pragma unroll
        for (int j = 0; j < 4; ++j)
          sm.tile[rowrel + j][col] = f2b(ac[j]);
      }
    }
    __syncthreads();
    #pragma unroll
    for (int it = 0; it < 4; ++it) {
      int rowrel = (tid >> 4) + it * 16;
      int grow = row0 + rowrel;
      uint4 v = *reinterpret_cast<const uint4*>(&sm.tile[rowrel][(tid & 15) * 8]);
      if (grow < NN)
        *reinterpret_cast<uint4*>(hx + ((size_t)r * NN + grow) * DD + (tid & 15) * 8) = v;
    }
    __syncthreads();
  }
}

// ------- per-bucket (128 nodes): deg, offs, rec = rowid<<13 | p13 ----------
// 1024 threads: 16 waves/block vs 4 -> hides nk-gather + exp latency
__global__ __launch_bounds__(1024) void k_bfinal(const unsigned* __restrict__ bedge,
    const int* __restrict__ bcur,
    const float* __restrict__ nq, const float* __restrict__ nk,
    int* __restrict__ deg, int* __restrict__ offs, unsigned* __restrict__ rec) {
  __shared__ int lh[128], sc_s[128], lcur[128];
  int b = blockIdx.x, tid = threadIdx.x;
  int base = b * CAP, cnt = bcur[b];
  if (tid < 128) lh[tid] = 0;
  __syncthreads();
  for (int i = tid; i < cnt; i += 1024)
    atomicAdd(&lh[(bedge[base + i] >> 22) & 127], 1);
  __syncthreads();
  int v = 0;
  if (tid < 128) { v = lh[tid]; sc_s[tid] = v; }
  __syncthreads();
  for (int off = 1; off < 128; off <<= 1) {
    int u = (tid < 128 && tid >= off) ? sc_s[tid - off] : 0;
    __syncthreads();
    if (tid < 128) sc_s[tid] += u;
    __syncthreads();
  }
  if (tid < 128) {
    int excl = sc_s[tid] - v;
    int n = (b << 7) + tid;
    if (n < NN) { deg[n] = v; offs[n] = base + excl; }
    lcur[tid] = base + excl;
  }
  __syncthreads();
  for (int i = tid; i < cnt; i += 1024) {
    unsigned be = bedge[base + i];
    unsigned rowid = (be >> 3) & 0x7FFFFu;
    int r = (int)(be & 7u);
    int dloc = (int)((be >> 22) & 127u);
    float l = nq[(size_t)r * NN + (b << 7) + dloc] + nk[rowid];
    l = l > 0.f ? l : NEG * l;
    float p = __expf(l);     // logits O(1): exp without max-sub is exact-safe
    unsigned pb = (__float_as_uint(p) + 0x20000u) >> 18;   // RTNE to 8e+5m
    int pos = atomicAdd(&lcur[dloc], 1);
    rec[pos] = (rowid << 13) | (pb & 0x1FFFu);
  }
}

// ------- gather-aggregate: p-weighted accumulate (8-deep, 32-lane) ---------
__global__ __launch_bounds__(256) void k_agg(const float* __restrict__ x,
    const float* __restrict__ bias, const int* __restrict__ offs,
    const int* __restrict__ deg, const unsigned* __restrict__ rec,
    const bf16* __restrict__ hx, float* __restrict__ out,
    float* __restrict__ irec) {
  int g = threadIdx.x >> 5, lane = threadIdx.x & 31;
  int n = blockIdx.x * 8 + g;
  if (n >= NN) return;
  int base = offs[n], cnt = deg[n];
  const char* hp = (const char*)hx;
  int lo8 = lane * 8;

  float ssum = 0.f;
  float a0 = 0.f, a1 = 0.f, a2 = 0.f, a3 = 0.f;

#define DEC(E, OFF, P) unsigned OFF = ((E) >> 5) & 0xFFFFFF00u; \
                       float P = __uint_as_float(((E) & 0x1FFFu) << 18);

  int j = 0;
  for (; j + 7 < cnt; j += 8) {
    unsigned e0 = rec[base + j],     e1 = rec[base + j + 1];
    unsigned e2 = rec[base + j + 2], e3 = rec[base + j + 3];
    unsigned e4 = rec[base + j + 4], e5 = rec[base + j + 5];
    unsigned e6 = rec[base + j + 6], e7 = rec[base + j + 7];
    DEC(e0, o0, p0) DEC(e1, o1, p1) DEC(e2, o2, p2) DEC(e3, o3, p3)
    DEC(e4, o4, p4) DEC(e5, o5, p5) DEC(e6, o6, p6) DEC(e7, o7, p7)
    uint2 q0 = *reinterpret_cast<const uint2*>(hp + o0 + lo8);
    uint2 q1 = *reinterpret_cast<const uint2*>(hp + o1 + lo8);
    uint2 q2 = *reinterpret_cast<const uint2*>(hp + o2 + lo8);
    uint2 q3 = *reinterpret_cast<const uint2*>(hp + o3 + lo8);
    uint2 q4 = *reinterpret_cast<const uint2*>(hp + o4 + lo8);
    uint2 q5 = *reinterpret_cast<const uint2*>(hp + o5 + lo8);
    uint2 q6 = *reinterpret_cast<const uint2*>(hp + o6 + lo8);
    uint2 q7 = *reinterpret_cast<const uint2*>(hp + o7 + lo8);
    ssum += ((p0 + p1) + (p2 + p3)) + ((p4 + p5) + (p6 + p7));
    a0 += p0 * bflo(q0.x) + p1 * bflo(q1.x) + p2 * bflo(q2.x) + p3 * bflo(q3.x)
        + p4 * bflo(q4.x) + p5 * bflo(q5.x) + p6 * bflo(q6.x) + p7 * bflo(q7.x);
    a1 += p0 * bfhi(q0.x) + p1 * bfhi(q1.x) + p2 * bfhi(q2.x) + p3 * bfhi(q3.x)
        + p4 * bfhi(q4.x) + p5 * bfhi(q5.x) + p6 * bfhi(q6.x) + p7 * bfhi(q7.x);
    a2 += p0 * bflo(q0.y) + p1 * bflo(q1.y) + p2 * bflo(q2.y) + p3 * bflo(q3.y)
        + p4 * bflo(q4.y) + p5 * bflo(q5.y) + p6 * bflo(q6.y) + p7 * bflo(q7.y);
    a3 += p0 * bfhi(q0.y) + p1 * bfhi(q1.y) + p2 * bfhi(q2.y) + p3 * bfhi(q3.y)
        + p4 * bfhi(q4.y) + p5 * bfhi(q5.y) + p6 * bfhi(q6.y) + p7 * bfhi(q7.y);
  }
  for (; j + 3 < cnt; j += 4) {
    unsigned e0 = rec[base + j],     e1 = rec[base + j + 1];
    unsigned e2 = rec[base + j + 2], e3 = rec[base + j + 3];
    DEC(e0, o0, p0) DEC(e1, o1, p1) DEC(e2, o2, p2) DEC(e3, o3, p3)
    uint2 q0 = *reinterpret_cast<const uint2*>(hp + o0 + lo8);
    uint2 q1 = *reinterpret_cast<const uint2*>(hp + o1 + lo8);
    uint2 q2 = *reinterpret_cast<const uint2*>(hp + o2 + lo8);
    uint2 q3 = *reinterpret_cast<const uint2*>(hp + o3 + lo8);
    ssum += (p0 + p1) + (p2 + p3);
    a0 += p0 * bflo(q0.x) + p1 * bflo(q1.x) + p2 * bflo(q2.x) + p3 * bflo(q3.x);
    a1 += p0 * bfhi(q0.x) + p1 * bfhi(q1.x) + p2 * bfhi(q2.x) + p3 * bfhi(q3.x);
    a2 += p0 * bflo(q0.y) + p1 * bflo(q1.y) + p2 * bflo(q2.y) + p3 * bflo(q3.y);
    a3 += p0 * bfhi(q0.y) + p1 * bfhi(q1.y) + p2 * bfhi(q2.y) + p3 * bfhi(q3.y);
  }
  for (; j < cnt; ++j) {
    unsigned e0 = rec[base + j];
    DEC(e0, o0, p0)
    uint2 q0 = *reinterpret_cast<const uint2*>(hp + o0 + lo8);
    ssum += p0;
    a0 += p0 * bflo(q0.x);
    a1 += p0 * bfhi(q0.x);
    a2 += p0 * bflo(q0.y);
    a3 += p0 * bfhi(q0.y);
  }
#undef DEC

  float inv = 1.f / (ssum + 1e-16f);
  size_t o = (size_t)n * DD + lane * 4;
  float4 xb = *reinterpret_cast<const float4*>(x + o);
  float4 bb = *reinterpret_cast<const float4*>(bias + lane * 4);
  float4 res;
  res.x = xb.x + bb.x + a0 * inv;
  res.y = xb.y + bb.y + a1 * inv;
  res.z = xb.z + bb.z + a2 * inv;
  res.w = xb.w + bb.w + a3 * inv;
  *reinterpret_cast<float4*>(out + o) = res;

  if (lane == 0) irec[n] = inv;
}

// ---------------- alpha in original edge order (2 edges/thread) ------------
__global__ __launch_bounds__(256) void k_alpha(const int* __restrict__ ei,
    const int* __restrict__ et, const float* __restrict__ nq,
    const float* __restrict__ nk, const float* __restrict__ irec,
    float* __restrict__ alpha) {
  int e = (blockIdx.x * 256 + threadIdx.x) * 2;
  if (e >= NE) return;   // NE even -> pair always complete
  int2 ss = *reinterpret_cast<const int2*>(ei + e);
  int2 dd = *reinterpret_cast<const int2*>(ei + NE + e);
  int2 rr = *reinterpret_cast<const int2*>(et + e);
  float l0 = nq[(size_t)rr.x * NN + dd.x] + nk[(size_t)rr.x * NN + ss.x];
  float l1 = nq[(size_t)rr.y * NN + dd.y] + nk[(size_t)rr.y * NN + ss.y];
  l0 = l0 > 0.f ? l0 : NEG * l0;
  l1 = l1 > 0.f ? l1 : NEG * l1;
  float2 res;
  res.x = __expf(l0) * irec[dd.x];
  res.y = __expf(l1) * irec[dd.y];
  *reinterpret_cast<float2*>(alpha + e) = res;
}

extern "C" void kernel_launch(void* const* d_in, const int* in_sizes, int n_in,
                              void* d_out, int out_size, void* d_ws, size_t ws_size,
                              hipStream_t stream) {
  const float* x    = (const float*)d_in[0];
  const int*   ei   = (const int*)d_in[1];
  const int*   et   = (const int*)d_in[2];
  const float* W    = (const float*)d_in[3];
  const float* qv   = (const float*)d_in[4];
  const float* kv   = (const float*)d_in[5];
  const float* bias = (const float*)d_in[6];

  float* out   = (float*)d_out;              // [NN*DD]
  float* alpha = out + (size_t)NN * DD;      // [NE]

  char* p = (char*)d_ws;
  bf16*  hx      = (bf16*)p;    p += (size_t)RR * NN * DD * sizeof(bf16); // 76.8 MB
  float* nq      = (float*)p;   p += (size_t)RR * NN * sizeof(float);
  float* nk      = (float*)p;   p += (size_t)RR * NN * sizeof(float);
  int*   deg     = (int*)p;     p += NN * sizeof(int);
  int*   offs    = (int*)p;     p += NN * sizeof(int);
  float* irec    = (float*)p;   p += NN * sizeof(float);
  int*   bcur    = (int*)p;     p += NB * sizeof(int);
  p = (char*)(((uintptr_t)p + 15) & ~(uintptr_t)15);
  unsigned* bedge = (unsigned*)p; p += (size_t)NB * CAP * sizeof(unsigned); // 6.4 MB
  unsigned* rec  = (unsigned*)p;  p += (size_t)NB * CAP * sizeof(unsigned); // 6.4 MB
  ushort* wp     = (ushort*)p;  p += (size_t)RR * 8 * 4 * 64 * 8 * sizeof(ushort); // 196 KB
  ushort* wp7    = (ushort*)p;  p += (size_t)4 * 64 * 8 * sizeof(ushort);          // 4 KB

  k_prep<<<49, 256, 0, stream>>>(W, qv, kv, wp, wp7, bcur);
  k_fused<<<GEMMB + SCB, 256, 0, stream>>>(x, wp, wp7, ei, et, bcur, bedge,
                                           (ushort*)hx, nq, nk);
  k_bfinal<<<NB, 1024, 0, stream>>>(bedge, bcur, nq, nk, deg, offs, rec);
  k_agg<<<(NN + 7) / 8, 256, 0, stream>>>(x, bias, offs, deg, rec, hx, out, irec);
  k_alpha<<<(NE / 2 + 255) / 256, 256, 0, stream>>>(ei, et, nq, nk, irec, alpha);
}